// Round 1
// baseline (671.686 us; speedup 1.0000x reference)
//
#include <hip/hip_runtime.h>
#include <math.h>

#define SEQ 2048
#define DM  1024
#define NH  16
#define HD  64

// ---------------------------------------------------------------------------
// GEMM: C[M][N] = A[M][K] * B[N][K]^T + bias[N]   (A,B,C row-major, fp32)
// 256 threads, BM=BN=128, BK=32, 8x8 register tile per thread.
// ---------------------------------------------------------------------------
template<int BM, int BN, int BK>
__global__ __launch_bounds__(256)
void gemm_nt_bias(const float* __restrict__ A, const float* __restrict__ B,
                  const float* __restrict__ bias, float* __restrict__ C,
                  int M, int N, int K) {
  constexpr int LDA = BM + 4;   // pad: keeps 16B alignment, breaks bank stride
  constexpr int LDB = BN + 4;
  __shared__ float As[BK][LDA]; // transposed: As[k][m]
  __shared__ float Bs[BK][LDB]; // transposed: Bs[k][n]

  const int t  = threadIdx.x;
  const int tx = t & 15;   // N direction (8 cols each)
  const int ty = t >> 4;   // M direction (8 rows each)
  const int bm = blockIdx.y * BM;
  const int bn = blockIdx.x * BN;

  float acc[8][8] = {};

  for (int k0 = 0; k0 < K; k0 += BK) {
    // stage A tile (BM x BK) transposed into LDS
    #pragma unroll
    for (int i = 0; i < (BM * BK) / (4 * 256); ++i) {
      int f   = t + i * 256;
      int row = f / (BK / 4);
      int cc  = f % (BK / 4);
      float4 a = *(const float4*)(A + (size_t)(bm + row) * K + k0 + cc * 4);
      As[cc * 4 + 0][row] = a.x;
      As[cc * 4 + 1][row] = a.y;
      As[cc * 4 + 2][row] = a.z;
      As[cc * 4 + 3][row] = a.w;
    }
    // stage B tile (BN x BK) transposed into LDS
    #pragma unroll
    for (int i = 0; i < (BN * BK) / (4 * 256); ++i) {
      int f   = t + i * 256;
      int row = f / (BK / 4);
      int cc  = f % (BK / 4);
      float4 b = *(const float4*)(B + (size_t)(bn + row) * K + k0 + cc * 4);
      Bs[cc * 4 + 0][row] = b.x;
      Bs[cc * 4 + 1][row] = b.y;
      Bs[cc * 4 + 2][row] = b.z;
      Bs[cc * 4 + 3][row] = b.w;
    }
    __syncthreads();

    #pragma unroll 8
    for (int kk = 0; kk < BK; ++kk) {
      float af[8], bf[8];
      *(float4*)&af[0] = *(const float4*)&As[kk][ty * 8];
      *(float4*)&af[4] = *(const float4*)&As[kk][ty * 8 + 4];
      *(float4*)&bf[0] = *(const float4*)&Bs[kk][tx * 8];
      *(float4*)&bf[4] = *(const float4*)&Bs[kk][tx * 8 + 4];
      #pragma unroll
      for (int i = 0; i < 8; ++i)
        #pragma unroll
        for (int j = 0; j < 8; ++j)
          acc[i][j] = fmaf(af[i], bf[j], acc[i][j]);
    }
    __syncthreads();
  }

  // epilogue: add bias, vectorized store
  float4 b0 = *(const float4*)(bias + bn + tx * 8);
  float4 b1 = *(const float4*)(bias + bn + tx * 8 + 4);
  #pragma unroll
  for (int i = 0; i < 8; ++i) {
    float4 o0 = { acc[i][0] + b0.x, acc[i][1] + b0.y,
                  acc[i][2] + b0.z, acc[i][3] + b0.w };
    float4 o1 = { acc[i][4] + b1.x, acc[i][5] + b1.y,
                  acc[i][6] + b1.z, acc[i][7] + b1.w };
    float* cr = C + (size_t)(bm + ty * 8 + i) * N + bn + tx * 8;
    *(float4*)cr       = o0;
    *(float4*)(cr + 4) = o1;
  }
}

// ---------------------------------------------------------------------------
// RoPE in-place on q and k sections of qkv[S][3*DM].
// Thread owns the (d, d+32) pair -> no race, no barrier needed.
// Non-interleaved rotate_half convention, angle = s * theta^(-d/32), d in [0,32)
// ---------------------------------------------------------------------------
__global__ __launch_bounds__(256)
void rope_kernel(float* __restrict__ qkv) {
  const int s = blockIdx.x;
  const int t = threadIdx.x;
  float* row = qkv + (size_t)s * (3 * DM);
  #pragma unroll
  for (int it = 0; it < 2; ++it) {
    int idx = t + it * 256;        // 0..511 -> (head, d-pair)
    int hh  = idx >> 5;            // 0..15
    int d   = idx & 31;            // 0..31
    // match reference: inv_freq = 1 / (theta ** (d/32))
    float inv = 1.0f / powf(10000.0f, (float)d * (1.0f / 32.0f));
    float ang = (float)s * inv;
    float sn, cs;
    sincosf(ang, &sn, &cs);
    float* q = row + hh * HD;
    float* k = row + DM + hh * HD;
    float q1 = q[d], q2 = q[d + 32];
    float k1 = k[d], k2 = k[d + 32];
    q[d]      = q1 * cs - q2 * sn;
    q[d + 32] = q2 * cs + q1 * sn;
    k[d]      = k1 * cs - k2 * sn;
    k[d + 32] = k2 * cs + k1 * sn;
  }
}

// ---------------------------------------------------------------------------
// Flash attention, fp32 VALU. One block = (head, 64-query tile).
// Scores computed transposed S[k][q] so the softmax row-reduction over keys is
// a 4-step __shfl_xor(4,8,16,32) entirely inside one 64-lane wave.
// qg = wave*4 + (lane&3) : query group (16 groups of 4)
// kg = lane>>2           : key group in scores, dim group in PV/output
// ---------------------------------------------------------------------------
__global__ __launch_bounds__(256)
void attn_kernel(const float* __restrict__ qkv, float* __restrict__ ctx) {
  constexpr int LDT = 68;  // pad for Qt/Kt ([d][q]/[d][k]) transposed tiles
  constexpr int LDP = 68;  // pad for Ps [q][k]
  __shared__ float Qt[HD][LDT];
  __shared__ float Kt[HD][LDT];
  __shared__ float Vs[64][HD];
  __shared__ float Ps[64][LDP];

  const int t    = threadIdx.x;
  const int lane = t & 63;
  const int wave = t >> 6;
  const int qg   = wave * 4 + (lane & 3);  // 0..15
  const int kg   = lane >> 2;              // 0..15
  const int h    = blockIdx.y;
  const int q0   = blockIdx.x * 64;

  const float* Qb = qkv + h * HD;
  const float* Kb = qkv + DM + h * HD;
  const float* Vb = qkv + 2 * DM + h * HD;

  // stage Q tile once, transposed [d][q], pre-scaled by 1/sqrt(hd)
  #pragma unroll
  for (int i = 0; i < 4; ++i) {
    int f = t + i * 256;
    int row = f >> 4, c = f & 15;
    float4 v = *(const float4*)(Qb + (size_t)(q0 + row) * (3 * DM) + c * 4);
    Qt[c * 4 + 0][row] = v.x * 0.125f;
    Qt[c * 4 + 1][row] = v.y * 0.125f;
    Qt[c * 4 + 2][row] = v.z * 0.125f;
    Qt[c * 4 + 3][row] = v.w * 0.125f;
  }

  float m[4], l[4];
  float o[4][4] = {};
  #pragma unroll
  for (int j = 0; j < 4; ++j) { m[j] = -3.0e38f; l[j] = 0.f; }

  #pragma unroll 1
  for (int kt = 0; kt < SEQ; kt += 64) {
    __syncthreads();  // protects Kt/Vs/Ps against previous iteration readers
                      // (and Q staging on the first iteration)
    // stage K transposed [d][k], V direct [k][d]
    #pragma unroll
    for (int i = 0; i < 4; ++i) {
      int f = t + i * 256;
      int row = f >> 4, c = f & 15;
      float4 kv = *(const float4*)(Kb + (size_t)(kt + row) * (3 * DM) + c * 4);
      Kt[c * 4 + 0][row] = kv.x;
      Kt[c * 4 + 1][row] = kv.y;
      Kt[c * 4 + 2][row] = kv.z;
      Kt[c * 4 + 3][row] = kv.w;
      float4 vv = *(const float4*)(Vb + (size_t)(kt + row) * (3 * DM) + c * 4);
      *(float4*)&Vs[row][c * 4] = vv;
    }
    __syncthreads();

    // scores S[k][q]: k = kg*4+i, q = qg*4+j (Q pre-scaled)
    float s_[4][4] = {};
    #pragma unroll 8
    for (int d = 0; d < HD; ++d) {
      float kf[4], qf[4];
      *(float4*)kf = *(const float4*)&Kt[d][kg * 4];
      *(float4*)qf = *(const float4*)&Qt[d][qg * 4];
      #pragma unroll
      for (int i = 0; i < 4; ++i)
        #pragma unroll
        for (int j = 0; j < 4; ++j)
          s_[i][j] = fmaf(kf[i], qf[j], s_[i][j]);
    }

    // online softmax per query column j; reduce across kg lanes (xor 4..32)
    #pragma unroll
    for (int j = 0; j < 4; ++j) {
      float cm = fmaxf(fmaxf(s_[0][j], s_[1][j]), fmaxf(s_[2][j], s_[3][j]));
      cm = fmaxf(cm, __shfl_xor(cm, 4));
      cm = fmaxf(cm, __shfl_xor(cm, 8));
      cm = fmaxf(cm, __shfl_xor(cm, 16));
      cm = fmaxf(cm, __shfl_xor(cm, 32));
      float mn = fmaxf(m[j], cm);
      float sc = __expf(m[j] - mn);   // first iter: exp(-inf)=0
      m[j] = mn;
      float rs = 0.f;
      #pragma unroll
      for (int i = 0; i < 4; ++i) {
        float p = __expf(s_[i][j] - mn);
        s_[i][j] = p;
        rs += p;
      }
      rs += __shfl_xor(rs, 4);
      rs += __shfl_xor(rs, 8);
      rs += __shfl_xor(rs, 16);
      rs += __shfl_xor(rs, 32);
      l[j] = l[j] * sc + rs;
      #pragma unroll
      for (int i = 0; i < 4; ++i) o[j][i] *= sc;
    }

    // write P to LDS as Ps[q][k] (float4 along k)
    #pragma unroll
    for (int j = 0; j < 4; ++j) {
      float4 w = { s_[0][j], s_[1][j], s_[2][j], s_[3][j] };
      *(float4*)&Ps[qg * 4 + j][kg * 4] = w;
    }
    __syncthreads();

    // PV: o[j][i], q = qg*4+j, dim = kg*4+i
    #pragma unroll 4
    for (int k0 = 0; k0 < 64; k0 += 4) {
      float pf[4][4], vf[4][4];
      #pragma unroll
      for (int j = 0; j < 4; ++j)
        *(float4*)pf[j] = *(const float4*)&Ps[qg * 4 + j][k0];
      #pragma unroll
      for (int c = 0; c < 4; ++c)
        *(float4*)vf[c] = *(const float4*)&Vs[k0 + c][kg * 4];
      #pragma unroll
      for (int j = 0; j < 4; ++j)
        #pragma unroll
        for (int i = 0; i < 4; ++i)
          #pragma unroll
          for (int c = 0; c < 4; ++c)
            o[j][i] = fmaf(pf[j][c], vf[c][i], o[j][i]);
    }
  }

  // epilogue: normalize and write ctx[s][h*64+d] (row-major [2048][1024])
  #pragma unroll
  for (int j = 0; j < 4; ++j) {
    float inv = 1.0f / l[j];
    float4 ov = { o[j][0] * inv, o[j][1] * inv, o[j][2] * inv, o[j][3] * inv };
    *(float4*)(ctx + (size_t)(q0 + qg * 4 + j) * DM + h * HD + kg * 4) = ov;
  }
}

// ---------------------------------------------------------------------------
extern "C" void kernel_launch(void* const* d_in, const int* in_sizes, int n_in,
                              void* d_out, int out_size, void* d_ws, size_t ws_size,
                              hipStream_t stream) {
  const float* query = (const float*)d_in[0];
  // d_in[1] (key), d_in[2] (value) are unused by the reference module
  const float* qkv_w = (const float*)d_in[3];
  const float* qkv_b = (const float*)d_in[4];
  const float* out_w = (const float*)d_in[5];
  const float* out_b = (const float*)d_in[6];
  float* out = (float*)d_out;

  float* qkv = (float*)d_ws;                       // [2048][3072]  24 MiB
  float* ctx = qkv + (size_t)SEQ * 3 * DM;         // [2048][1024]   8 MiB

  // 1) QKV projection: qkv = query @ qkv_w^T + qkv_b
  gemm_nt_bias<128, 128, 32><<<dim3(3 * DM / 128, SEQ / 128), 256, 0, stream>>>(
      query, qkv_w, qkv_b, qkv, SEQ, 3 * DM, DM);

  // 2) RoPE in-place on q,k sections
  rope_kernel<<<SEQ, 256, 0, stream>>>(qkv);

  // 3) flash attention -> ctx [s][h*hd+d]
  attn_kernel<<<dim3(SEQ / 64, NH), 256, 0, stream>>>(qkv, ctx);

  // 4) output projection: out = ctx @ out_w^T + out_b
  gemm_nt_bias<128, 128, 32><<<dim3(DM / 128, SEQ / 128), 256, 0, stream>>>(
      ctx, out_w, out_b, out, SEQ, DM, DM);
}

// Round 2
// 124.710 us; speedup vs baseline: 5.3860x; 5.3860x over previous
//
#include <hip/hip_runtime.h>
#include <math.h>
#include <stdint.h>

#define SEQ 2048
#define DM  1024
#define NH  16
#define HD  64
#define TRI 3072  // 3*DM

typedef _Float16 half8 __attribute__((ext_vector_type(8)));
typedef float f32x4 __attribute__((ext_vector_type(4)));

// global -> LDS direct 16B copy. LDS dest must be wave-uniform; HW adds lane*16.
#define GLOAD_LDS16(g, l)                                       \
  __builtin_amdgcn_global_load_lds(                             \
      (__attribute__((address_space(1))) void*)(g),             \
      (__attribute__((address_space(3))) void*)(l), 16, 0, 0)

// ---------------------------------------------------------------------------
// fp32 -> fp16 conversion for query / qkv_w / out_w (one fused kernel)
// ---------------------------------------------------------------------------
__global__ __launch_bounds__(256)
void cvt3(const float* __restrict__ s1, const float* __restrict__ s2,
          const float* __restrict__ s3, _Float16* __restrict__ d1,
          _Float16* __restrict__ d2, _Float16* __restrict__ d3,
          int n1, int n2) {
  int i = (blockIdx.x * 256 + threadIdx.x) * 4;
  const float* s; _Float16* d;
  if (i < n1)            { s = s1; d = d1; }
  else if (i < n1 + n2)  { s = s2; d = d2; i -= n1; }
  else                   { s = s3; d = d3; i -= n1 + n2; }
  float4 v = *(const float4*)(s + i);
  union { _Float16 h[4]; uint2 u; } pk;
  pk.h[0] = (_Float16)v.x; pk.h[1] = (_Float16)v.y;
  pk.h[2] = (_Float16)v.z; pk.h[3] = (_Float16)v.w;
  *(uint2*)(d + i) = pk.u;
}

// ---------------------------------------------------------------------------
// C[M][N] = A[M][K] (fp16) * B[N][K]^T (fp16) + bias[N] (fp32), fp32 accum.
// 128x128 tile, BK=32, 4 waves (each a 64x64 quadrant, 4x4 16x16x32 frags).
// Staging: global_load_lds dwordx4, linear LDS (m97 structure).
// ---------------------------------------------------------------------------
template<typename OutT>
__global__ __launch_bounds__(256)
void gemm_f16_nt(const _Float16* __restrict__ A, const _Float16* __restrict__ B,
                 const float* __restrict__ bias, OutT* __restrict__ C,
                 int M, int N, int K) {
  __shared__ _Float16 As[128 * 32];
  __shared__ _Float16 Bs[128 * 32];

  const int t    = threadIdx.x;
  const int lane = t & 63;
  const int wv   = t >> 6;
  const int l15  = lane & 15;
  const int l4   = lane >> 4;
  const int wr   = wv >> 1, wc = wv & 1;
  const int bm   = blockIdx.y * 128, bn = blockIdx.x * 128;

  f32x4 acc[4][4] = {};

  for (int k0 = 0; k0 < K; k0 += 32) {
    __syncthreads();
    #pragma unroll
    for (int i = 0; i < 2; ++i) {
      int c = t + i * 256;               // 16B chunk id: row=c>>2, cb=c&3
      int row = c >> 2, cb = c & 3;
      char* ldsA = (char*)As + (size_t)(i * 256 + wv * 64) * 16;
      GLOAD_LDS16(A + (size_t)(bm + row) * K + k0 + cb * 8, ldsA);
      char* ldsB = (char*)Bs + (size_t)(i * 256 + wv * 64) * 16;
      GLOAD_LDS16(B + (size_t)(bn + row) * K + k0 + cb * 8, ldsB);
    }
    __syncthreads();

    half8 af[4], bf[4];
    #pragma unroll
    for (int mf = 0; mf < 4; ++mf)
      af[mf] = *(const half8*)(As + (wr * 64 + mf * 16 + l15) * 32 + l4 * 8);
    #pragma unroll
    for (int nf = 0; nf < 4; ++nf)
      bf[nf] = *(const half8*)(Bs + (wc * 64 + nf * 16 + l15) * 32 + l4 * 8);
    #pragma unroll
    for (int mf = 0; mf < 4; ++mf)
      #pragma unroll
      for (int nf = 0; nf < 4; ++nf)
        acc[mf][nf] = __builtin_amdgcn_mfma_f32_16x16x32_f16(
            af[mf], bf[nf], acc[mf][nf], 0, 0, 0);
  }

  float bv[4];
  #pragma unroll
  for (int nf = 0; nf < 4; ++nf) bv[nf] = bias[bn + wc * 64 + nf * 16 + l15];
  #pragma unroll
  for (int mf = 0; mf < 4; ++mf)
    #pragma unroll
    for (int nf = 0; nf < 4; ++nf)
      #pragma unroll
      for (int r = 0; r < 4; ++r) {
        int row = bm + wr * 64 + mf * 16 + l4 * 4 + r;  // C/D: row=(l>>4)*4+reg
        int col = bn + wc * 64 + nf * 16 + l15;         //      col=lane&15
        C[(size_t)row * N + col] = (OutT)(acc[mf][nf][r] + bv[nf]);
      }
}

// ---------------------------------------------------------------------------
// RoPE in-place on fp16 qkv [S][3*DM]; q additionally scaled by 1/sqrt(HD).
// ---------------------------------------------------------------------------
__global__ __launch_bounds__(256)
void rope_f16(_Float16* __restrict__ qkv) {
  const int s = blockIdx.x, t = threadIdx.x;
  _Float16* row = qkv + (size_t)s * TRI;
  #pragma unroll
  for (int it = 0; it < 2; ++it) {
    int idx = t + it * 256;
    int hh = idx >> 5, d = idx & 31;
    // inv_freq = theta^(-d/32) = exp2(-d * log2(1e4)/32)
    float inv = exp2f((float)d * -0.4152410118609203f);
    float ang = (float)s * inv;
    float sn, cs;
    sincosf(ang, &sn, &cs);
    _Float16* q = row + hh * HD;
    _Float16* k = row + DM + hh * HD;
    float q1 = (float)q[d], q2 = (float)q[d + 32];
    float k1 = (float)k[d], k2 = (float)k[d + 32];
    q[d]      = (_Float16)((q1 * cs - q2 * sn) * 0.125f);
    q[d + 32] = (_Float16)((q2 * cs + q1 * sn) * 0.125f);
    k[d]      = (_Float16)(k1 * cs - k2 * sn);
    k[d + 32] = (_Float16)(k2 * cs + k1 * sn);
  }
}

// ---------------------------------------------------------------------------
// MFMA flash attention. Block = (64-q tile, head), 4 waves (16 q-rows each).
// S^T = K.Q^T  (C-layout: row=k, col=q=lane&15) -> per-lane softmax over k
// with xor-16/32 shuffles only. P -> per-wave LDS -> A-frag; PV with V
// reg-staged transposed into padded Vt[64][72].
// ---------------------------------------------------------------------------
__global__ __launch_bounds__(256)
void attn_f16(const _Float16* __restrict__ qkv, _Float16* __restrict__ ctx) {
  __shared__ _Float16 Klds[64 * 64];     // chunk-swizzled: chunk p = cb^(r&7)
  __shared__ _Float16 Vt[64 * 72];       // V^T, padded rows (8-slot banks)
  __shared__ _Float16 Plds[4][16 * 72];  // per-wave P

  const int t = threadIdx.x, lane = t & 63, wv = t >> 6;
  const int l15 = lane & 15, l4 = lane >> 4;
  const int h  = blockIdx.y;
  const int q0 = blockIdx.x * 64;

  const _Float16* Qb = qkv + h * HD;
  const _Float16* Kb = qkv + DM + h * HD;
  const _Float16* Vb = qkv + 2 * DM + h * HD;

  // Q B-frags in registers (q pre-scaled by 0.125 in rope)
  half8 qf[2];
  {
    const _Float16* qrow = Qb + (size_t)(q0 + wv * 16 + l15) * TRI;
    qf[0] = *(const half8*)(qrow + l4 * 8);
    qf[1] = *(const half8*)(qrow + 32 + l4 * 8);
  }

  float mrun = -3.0e38f, lrun = 0.0f;
  f32x4 o[4] = {};
  _Float16* Pw = Plds[wv];

  for (int kt = 0; kt < SEQ; kt += 64) {
    __syncthreads();
    // stage K (global_load_lds, src-swizzled) and V^T (reg-staged, 2-way free)
    #pragma unroll
    for (int i = 0; i < 2; ++i) {
      int c = t + i * 256;
      int r = c >> 3, p = c & 7;
      char* ldst = (char*)Klds + (size_t)(i * 256 + wv * 64) * 16;
      GLOAD_LDS16(Kb + (size_t)(kt + r) * TRI + ((p ^ (r & 7)) * 8), ldst);
      int k = c & 63, db = (c >> 6) * 8;
      half8 vv = *(const half8*)(Vb + (size_t)(kt + k) * TRI + db);
      #pragma unroll
      for (int j = 0; j < 8; ++j)
        Vt[(db + j) * 72 + k] = vv[j];
    }
    __syncthreads();

    // S^T = K . Q^T
    f32x4 sT[4] = {};
    #pragma unroll
    for (int ds = 0; ds < 2; ++ds)
      #pragma unroll
      for (int mf = 0; mf < 4; ++mf) {
        int r  = mf * 16 + l15;
        int cb = ds * 4 + l4;
        half8 kf = *(const half8*)(Klds + r * 64 + ((cb ^ (r & 7)) * 8));
        sT[mf] = __builtin_amdgcn_mfma_f32_16x16x32_f16(kf, qf[ds], sT[mf], 0, 0, 0);
      }

    // online softmax over k for q = l15 (16 vals/lane + xor16/32)
    float mloc = sT[0][0];
    #pragma unroll
    for (int mf = 0; mf < 4; ++mf)
      #pragma unroll
      for (int r = 0; r < 4; ++r) mloc = fmaxf(mloc, sT[mf][r]);
    mloc = fmaxf(mloc, __shfl_xor(mloc, 16));
    mloc = fmaxf(mloc, __shfl_xor(mloc, 32));
    float mn   = fmaxf(mrun, mloc);
    float corr = __expf(mrun - mn);       // first tile: exp(-huge) = 0
    mrun = mn;
    float ls = 0.f;
    #pragma unroll
    for (int mf = 0; mf < 4; ++mf)
      #pragma unroll
      for (int r = 0; r < 4; ++r) {
        float p = __expf(sT[mf][r] - mn);
        sT[mf][r] = p;
        ls += p;
      }
    ls += __shfl_xor(ls, 16);
    ls += __shfl_xor(ls, 32);
    lrun = lrun * corr + ls;

    // rescale o: o holds q' = l4*4+r -> fetch corr from lane q'
    float cr[4];
    #pragma unroll
    for (int r = 0; r < 4; ++r) cr[r] = __shfl(corr, l4 * 4 + r);
    #pragma unroll
    for (int nf = 0; nf < 4; ++nf)
      #pragma unroll
      for (int r = 0; r < 4; ++r) o[nf][r] *= cr[r];

    // P -> per-wave LDS (fp16), k packed 4-wide per write
    #pragma unroll
    for (int mf = 0; mf < 4; ++mf) {
      union { _Float16 hh[4]; uint2 u; } pk;
      #pragma unroll
      for (int r = 0; r < 4; ++r) pk.hh[r] = (_Float16)sT[mf][r];
      *(uint2*)(Pw + l15 * 72 + mf * 16 + l4 * 4) = pk.u;
    }

    // PV: o[nf] += P[16q x 32k] . V[32k x 16d]
    #pragma unroll
    for (int ks = 0; ks < 2; ++ks) {
      half8 pa = *(const half8*)(Pw + l15 * 72 + ks * 32 + l4 * 8);
      #pragma unroll
      for (int nf = 0; nf < 4; ++nf) {
        half8 vb = *(const half8*)(Vt + (nf * 16 + l15) * 72 + ks * 32 + l4 * 8);
        o[nf] = __builtin_amdgcn_mfma_f32_16x16x32_f16(pa, vb, o[nf], 0, 0, 0);
      }
    }
  }

  // epilogue: normalize (l for q' fetched cross-lane), store ctx fp16
  float lr[4];
  #pragma unroll
  for (int r = 0; r < 4; ++r) lr[r] = 1.0f / __shfl(lrun, l4 * 4 + r);
  #pragma unroll
  for (int nf = 0; nf < 4; ++nf)
    #pragma unroll
    for (int r = 0; r < 4; ++r) {
      int row = q0 + wv * 16 + l4 * 4 + r;
      int col = h * HD + nf * 16 + l15;
      ctx[(size_t)row * DM + col] = (_Float16)(o[nf][r] * lr[r]);
    }
}

// ---------------------------------------------------------------------------
extern "C" void kernel_launch(void* const* d_in, const int* in_sizes, int n_in,
                              void* d_out, int out_size, void* d_ws, size_t ws_size,
                              hipStream_t stream) {
  const float* query = (const float*)d_in[0];
  const float* qkv_w = (const float*)d_in[3];
  const float* qkv_b = (const float*)d_in[4];
  const float* out_w = (const float*)d_in[5];
  const float* out_b = (const float*)d_in[6];
  float* out = (float*)d_out;

  _Float16* Aq   = (_Float16*)d_ws;                 // 2048x1024   4 MiB
  _Float16* Wqkv = Aq + (size_t)SEQ * DM;           // 3072x1024   6 MiB
  _Float16* Wout = Wqkv + (size_t)TRI * DM;         // 1024x1024   2 MiB
  _Float16* qkv  = Wout + (size_t)DM * DM;          // 2048x3072  12 MiB
  _Float16* ctx  = qkv + (size_t)SEQ * TRI;         // 2048x1024   4 MiB

  cvt3<<<6144, 256, 0, stream>>>(query, qkv_w, out_w, Aq, Wqkv, Wout,
                                 SEQ * DM, TRI * DM);

  gemm_f16_nt<_Float16><<<dim3(TRI / 128, SEQ / 128), 256, 0, stream>>>(
      Aq, Wqkv, qkv_b, qkv, SEQ, TRI, DM);

  rope_f16<<<SEQ, 256, 0, stream>>>(qkv);

  attn_f16<<<dim3(SEQ / 64, NH), 256, 0, stream>>>(qkv, ctx);

  gemm_f16_nt<float><<<dim3(DM / 128, SEQ / 128), 256, 0, stream>>>(
      ctx, Wout, out_b, out, SEQ, DM, DM);
}

// Round 3
// 114.605 us; speedup vs baseline: 5.8609x; 1.0882x over previous
//
#include <hip/hip_runtime.h>
#include <math.h>
#include <stdint.h>

#define SEQ 2048
#define DM  1024
#define NH  16
#define HD  64
#define TRI 3072  // 3*DM

typedef _Float16 half8 __attribute__((ext_vector_type(8)));
typedef float f32x4 __attribute__((ext_vector_type(4)));

// global -> LDS direct 16B copy. LDS dest is wave-uniform base; HW adds lane*16.
#define GLOAD_LDS16(g, l)                                       \
  __builtin_amdgcn_global_load_lds(                             \
      (__attribute__((address_space(1))) void*)(g),             \
      (__attribute__((address_space(3))) void*)(l), 16, 0, 0)

// ---------------------------------------------------------------------------
// fp32 -> fp16 conversion (query/qkv_w/out_w) + RoPE cos/sin table fill.
// Blocks [0,6144): convert; blocks [6144,6400): fill tab[2048][32] = (cos,sin).
// ---------------------------------------------------------------------------
__global__ __launch_bounds__(256)
void cvt3(const float* __restrict__ s1, const float* __restrict__ s2,
          const float* __restrict__ s3, _Float16* __restrict__ d1,
          _Float16* __restrict__ d2, _Float16* __restrict__ d3,
          float2* __restrict__ tab, int n1, int n2) {
  int b = blockIdx.x;
  if (b >= 6144) {
    int i = (b - 6144) * 256 + threadIdx.x;     // 0..65535 -> (s, d)
    int s = i >> 5, d = i & 31;
    // inv_freq = theta^(-d/32) = exp2(-d * log2(1e4)/32)
    float inv = exp2f((float)d * -0.4152410118609203f);
    float ang = (float)s * inv;
    float sn, cs;
    sincosf(ang, &sn, &cs);
    tab[i] = make_float2(cs, sn);
    return;
  }
  int i = (b * 256 + threadIdx.x) * 4;
  const float* s; _Float16* d;
  if (i < n1)            { s = s1; d = d1; }
  else if (i < n1 + n2)  { s = s2; d = d2; i -= n1; }
  else                   { s = s3; d = d3; i -= n1 + n2; }
  float4 v = *(const float4*)(s + i);
  union { _Float16 h[4]; uint2 u; } pk;
  pk.h[0] = (_Float16)v.x; pk.h[1] = (_Float16)v.y;
  pk.h[2] = (_Float16)v.z; pk.h[3] = (_Float16)v.w;
  *(uint2*)(d + i) = pk.u;
}

// ---------------------------------------------------------------------------
// C[M][N] = A[M][K] (fp16) * B[N][K]^T (fp16) + bias[N], fp32 accum.
// 64x128 tile, BK=32, 4 waves (2M x 2N quadrants of 32x64), double-buffered
// LDS with one barrier per k-step; gload_lds staging.
// ROPE=1: fuse RoPE on q/k sections (N=3072 qkv layout) + 1/8 scale on q.
// ---------------------------------------------------------------------------
template<int ROPE, typename OutT>
__global__ __launch_bounds__(256)
void gemm_dbuf(const _Float16* __restrict__ A, const _Float16* __restrict__ B,
               const float* __restrict__ bias, const float2* __restrict__ tab,
               OutT* __restrict__ C, int M, int N, int K) {
  __shared__ _Float16 As[2][64 * 32];
  __shared__ _Float16 Bs[2][128 * 32];

  const int t = threadIdx.x, lane = t & 63, wv = t >> 6;
  const int l15 = lane & 15, l4 = lane >> 4;
  const int wr = wv >> 1, wc = wv & 1;
  const int bm = blockIdx.y * 64, bn = blockIdx.x * 128;

  auto stage = [&](int buf, int k0) {
    {
      int c = t;  // 256 chunks: row = c>>2 (64 rows), cb = c&3
      GLOAD_LDS16(A + (size_t)(bm + (c >> 2)) * K + k0 + (c & 3) * 8,
                  (char*)&As[buf][wv * 512]);
    }
    #pragma unroll
    for (int i = 0; i < 2; ++i) {
      int c = t + i * 256;  // 512 chunks: row = c>>2 (128 rows)
      GLOAD_LDS16(B + (size_t)(bn + (c >> 2)) * K + k0 + (c & 3) * 8,
                  (char*)&Bs[buf][(i * 256 + wv * 64) * 8]);
    }
  };

  f32x4 acc[2][4] = {};
  stage(0, 0);
  __syncthreads();

  const int nk = K / 32;
  for (int s = 0; s < nk; ++s) {
    int cur = s & 1;
    if (s + 1 < nk) stage(cur ^ 1, (s + 1) * 32);
    half8 af[2], bf[4];
    #pragma unroll
    for (int mf = 0; mf < 2; ++mf)
      af[mf] = *(const half8*)&As[cur][(wr * 32 + mf * 16 + l15) * 32 + l4 * 8];
    #pragma unroll
    for (int nf = 0; nf < 4; ++nf)
      bf[nf] = *(const half8*)&Bs[cur][(wc * 64 + nf * 16 + l15) * 32 + l4 * 8];
    __builtin_amdgcn_s_setprio(1);
    #pragma unroll
    for (int mf = 0; mf < 2; ++mf)
      #pragma unroll
      for (int nf = 0; nf < 4; ++nf)
        acc[mf][nf] = __builtin_amdgcn_mfma_f32_16x16x32_f16(
            af[mf], bf[nf], acc[mf][nf], 0, 0, 0);
    __builtin_amdgcn_s_setprio(0);
    __syncthreads();  // drains prefetch DMA (vmcnt) + frag reads; swap buffers
  }

  // epilogue: bias (+ fused RoPE on q/k sections), scalar stores (col stride 16)
  const int sec = ROPE ? (bn >> 10) : 2;  // 0=q, 1=k, 2=v
  float bv[4];
  #pragma unroll
  for (int nf = 0; nf < 4; ++nf) bv[nf] = bias[bn + wc * 64 + nf * 16 + l15];
  #pragma unroll
  for (int mf = 0; mf < 2; ++mf)
    #pragma unroll
    for (int r = 0; r < 4; ++r) {
      int row = bm + wr * 32 + mf * 16 + l4 * 4 + r;  // C/D: row=(l>>4)*4+reg
      float v0 = acc[mf][0][r] + bv[0];
      float v1 = acc[mf][1][r] + bv[1];
      float v2 = acc[mf][2][r] + bv[2];
      float v3 = acc[mf][3][r] + bv[3];
      if (ROPE && sec < 2) {
        // head-aligned quadrant: d = nf*16+l15; pair (d, d+32) = (nf, nf+2)
        float2 cs0 = tab[row * 32 + l15];
        float2 cs1 = tab[row * 32 + 16 + l15];
        float a0 = v0 * cs0.x - v2 * cs0.y;
        float a2 = v2 * cs0.x + v0 * cs0.y;
        float a1 = v1 * cs1.x - v3 * cs1.y;
        float a3 = v3 * cs1.x + v1 * cs1.y;
        if (sec == 0) { a0 *= 0.125f; a1 *= 0.125f; a2 *= 0.125f; a3 *= 0.125f; }
        v0 = a0; v1 = a1; v2 = a2; v3 = a3;
      }
      OutT* cr = C + (size_t)row * N + bn + wc * 64 + l15;
      cr[0]  = (OutT)v0; cr[16] = (OutT)v1;
      cr[32] = (OutT)v2; cr[48] = (OutT)v3;
    }
}

// ---------------------------------------------------------------------------
// MFMA flash attention, double-buffered K/V, one barrier per 64-key tile.
// S^T = K.Q^T (lane l15 = q) -> softmax per-lane over k, xor-16/32 reduce.
// V prefetched to regs, 4x4 dword shfl-transpose, ds_write_b64 into
// chunk-XOR-swizzled Vt[d][k]; K via gload_lds with src pre-swizzle.
// ---------------------------------------------------------------------------
__global__ __launch_bounds__(256)
void attn_f16(const _Float16* __restrict__ qkv, _Float16* __restrict__ ctx) {
  __shared__ _Float16 Kl[2][64 * 64];   // [k][d], 16B chunk p stored at p^(k&7)
  __shared__ _Float16 Vt[2][64 * 64];   // [d][k], 16B chunk p stored at p^(d&7)
  __shared__ _Float16 Pl[4][16 * 72];   // per-wave P [q][k]

  const int t = threadIdx.x, lane = t & 63, wv = t >> 6;
  const int l15 = lane & 15, l4 = lane >> 4;
  const int h = blockIdx.y, q0 = blockIdx.x * 64;

  const _Float16* Qb = qkv + h * HD;
  const _Float16* Kb = qkv + DM + h * HD;
  const _Float16* Vb = qkv + 2 * DM + h * HD;

  half8 qf[2];
  {
    const _Float16* qrow = Qb + (size_t)(q0 + wv * 16 + l15) * TRI;
    qf[0] = *(const half8*)(qrow + l4 * 8);
    qf[1] = *(const half8*)(qrow + 32 + l4 * 8);
  }

  uint4 vreg[2];

  auto issueK = [&](int buf, int kt) {
    #pragma unroll
    for (int i = 0; i < 2; ++i) {
      int c = t + i * 256, r = c >> 3, p = c & 7;
      GLOAD_LDS16(Kb + (size_t)(kt + r) * TRI + ((p ^ (r & 7)) * 8),
                  (char*)&Kl[buf][(i * 256 + wv * 64) * 8]);
    }
  };
  auto issueV = [&](int kt) {
    #pragma unroll
    for (int i = 0; i < 2; ++i)
      vreg[i] = *(const uint4*)(Vb + (size_t)(kt + lane) * TRI + (wv + i * 4) * 8);
  };
  auto writeV = [&](int buf) {
    const int m = lane & 3, k0 = lane & 60;
    #pragma unroll
    for (int i = 0; i < 2; ++i) {
      uint32_t u0 = vreg[i].x, u1 = vreg[i].y, u2 = vreg[i].z, u3 = vreg[i].w;
      // 4x4 dword transpose across quad lanes (swap bit0 then bit1)
      uint32_t s0 = __shfl_xor(u1, 1), s1 = __shfl_xor(u0, 1);
      uint32_t s2 = __shfl_xor(u3, 1), s3 = __shfl_xor(u2, 1);
      bool b0 = (m & 1);
      uint32_t a0 = b0 ? s0 : u0, a1 = b0 ? u1 : s1;
      uint32_t a2 = b0 ? s2 : u2, a3 = b0 ? u3 : s3;
      uint32_t r0 = __shfl_xor(a2, 2), r1 = __shfl_xor(a3, 2);
      uint32_t r2 = __shfl_xor(a0, 2), r3 = __shfl_xor(a1, 2);
      bool b1 = (m & 2);
      uint32_t w0 = b1 ? r0 : a0, w1 = b1 ? r1 : a1;
      uint32_t w2 = b1 ? a2 : r2, w3 = b1 ? a3 : r3;
      // w[j] = (V[k0+j][d0], V[k0+j][d0+1]); split halves into rows d0, d0+1
      int d0 = (wv + i * 4) * 8 + 2 * m;
      uint32_t lo01 = (w0 & 0xffffu) | (w1 << 16);
      uint32_t lo23 = (w2 & 0xffffu) | (w3 << 16);
      uint32_t hi01 = (w0 >> 16) | (w1 & 0xffff0000u);
      uint32_t hi23 = (w2 >> 16) | (w3 & 0xffff0000u);
      char* base = (char*)Vt[buf];
      int hb = ((k0 >> 2) & 1) * 8;
      *(uint2*)(base + d0 * 128 + (((k0 >> 3) ^ (d0 & 7)) * 16) + hb) =
          make_uint2(lo01, lo23);
      *(uint2*)(base + (d0 + 1) * 128 + (((k0 >> 3) ^ ((d0 + 1) & 7)) * 16) + hb) =
          make_uint2(hi01, hi23);
    }
  };

  float mrun = -3.0e38f, lrun = 0.0f;
  f32x4 o[4] = {};
  _Float16* Pw = Pl[wv];

  issueK(0, 0);
  issueV(0);
  writeV(0);
  __syncthreads();

  const int NT = SEQ / 64;
  for (int tt = 0; tt < NT; ++tt) {
    const int cur = tt & 1;
    const bool pf = (tt + 1 < NT);
    if (pf) { issueK(cur ^ 1, (tt + 1) * 64); issueV((tt + 1) * 64); }

    // S^T = K . Q^T
    f32x4 sT[4] = {};
    __builtin_amdgcn_s_setprio(1);
    #pragma unroll
    for (int ds = 0; ds < 2; ++ds)
      #pragma unroll
      for (int mf = 0; mf < 4; ++mf) {
        int r = mf * 16 + l15;
        int cb = ds * 4 + l4;
        half8 kf = *(const half8*)(&Kl[cur][r * 64 + ((cb ^ (r & 7)) * 8)]);
        sT[mf] = __builtin_amdgcn_mfma_f32_16x16x32_f16(kf, qf[ds], sT[mf], 0, 0, 0);
      }
    __builtin_amdgcn_s_setprio(0);

    // online softmax over k for q = l15, with defer-max (THR=8)
    float mloc = sT[0][0];
    #pragma unroll
    for (int mf = 0; mf < 4; ++mf)
      #pragma unroll
      for (int r = 0; r < 4; ++r) mloc = fmaxf(mloc, sT[mf][r]);
    mloc = fmaxf(mloc, __shfl_xor(mloc, 16));
    mloc = fmaxf(mloc, __shfl_xor(mloc, 32));
    float corr = 1.0f;
    if (!__all(mloc - mrun <= 8.0f)) {
      float mn = fmaxf(mrun, mloc);
      corr = __expf(mrun - mn);   // first tile: exp(-huge) = 0
      mrun = mn;
      float cr[4];
      #pragma unroll
      for (int r = 0; r < 4; ++r) cr[r] = __shfl(corr, l4 * 4 + r);
      #pragma unroll
      for (int nf = 0; nf < 4; ++nf)
        #pragma unroll
        for (int r = 0; r < 4; ++r) o[nf][r] *= cr[r];
    }
    float ls = 0.f;
    #pragma unroll
    for (int mf = 0; mf < 4; ++mf)
      #pragma unroll
      for (int r = 0; r < 4; ++r) {
        float p = __expf(sT[mf][r] - mrun);
        sT[mf][r] = p;
        ls += p;
      }
    ls += __shfl_xor(ls, 16);
    ls += __shfl_xor(ls, 32);
    lrun = lrun * corr + ls;

    // P -> per-wave LDS (fp16, bounded by e^8 under defer)
    #pragma unroll
    for (int mf = 0; mf < 4; ++mf) {
      union { _Float16 hh[4]; uint2 u; } pk;
      #pragma unroll
      for (int r = 0; r < 4; ++r) pk.hh[r] = (_Float16)sT[mf][r];
      *(uint2*)(Pw + l15 * 72 + mf * 16 + l4 * 4) = pk.u;
    }

    if (pf) writeV(cur ^ 1);  // write-late: vreg latency hidden under QK^T+softmax

    // PV: o[nf] += P[16q x 32k] . V[32k x 16d]
    __builtin_amdgcn_s_setprio(1);
    #pragma unroll
    for (int ks = 0; ks < 2; ++ks) {
      half8 pa = *(const half8*)(Pw + l15 * 72 + ks * 32 + l4 * 8);
      #pragma unroll
      for (int nf = 0; nf < 4; ++nf) {
        int d = nf * 16 + l15;
        half8 vb = *(const half8*)((char*)Vt[cur] + d * 128 +
                                   (((ks * 4 + l4) ^ (d & 7)) * 16));
        o[nf] = __builtin_amdgcn_mfma_f32_16x16x32_f16(pa, vb, o[nf], 0, 0, 0);
      }
    }
    __builtin_amdgcn_s_setprio(0);
    __syncthreads();  // drains K-DMA (vmcnt) + V ds_writes (lgkm); swap buffers
  }

  // epilogue: normalize and store ctx [s][h*64+d]
  float lr[4];
  #pragma unroll
  for (int r = 0; r < 4; ++r) lr[r] = 1.0f / __shfl(lrun, l4 * 4 + r);
  #pragma unroll
  for (int nf = 0; nf < 4; ++nf)
    #pragma unroll
    for (int r = 0; r < 4; ++r) {
      int row = q0 + wv * 16 + l4 * 4 + r;
      int col = h * HD + nf * 16 + l15;
      ctx[(size_t)row * DM + col] = (_Float16)(o[nf][r] * lr[r]);
    }
}

// ---------------------------------------------------------------------------
extern "C" void kernel_launch(void* const* d_in, const int* in_sizes, int n_in,
                              void* d_out, int out_size, void* d_ws, size_t ws_size,
                              hipStream_t stream) {
  const float* query = (const float*)d_in[0];
  const float* qkv_w = (const float*)d_in[3];
  const float* qkv_b = (const float*)d_in[4];
  const float* out_w = (const float*)d_in[5];
  const float* out_b = (const float*)d_in[6];
  float* out = (float*)d_out;

  _Float16* Aq   = (_Float16*)d_ws;                 // 2048x1024   4 MiB
  _Float16* Wqkv = Aq + (size_t)SEQ * DM;           // 3072x1024   6 MiB
  _Float16* Wout = Wqkv + (size_t)TRI * DM;         // 1024x1024   2 MiB
  _Float16* qkv  = Wout + (size_t)DM * DM;          // 2048x3072  12 MiB
  _Float16* ctx  = qkv + (size_t)SEQ * TRI;         // 2048x1024   4 MiB
  float2*   tab  = (float2*)(ctx + (size_t)SEQ * DM); // 2048x32   512 KiB

  cvt3<<<6400, 256, 0, stream>>>(query, qkv_w, out_w, Aq, Wqkv, Wout, tab,
                                 SEQ * DM, TRI * DM);

  gemm_dbuf<1, _Float16><<<dim3(TRI / 128, SEQ / 64), 256, 0, stream>>>(
      Aq, Wqkv, qkv_b, tab, qkv, SEQ, TRI, DM);

  attn_f16<<<dim3(SEQ / 64, NH), 256, 0, stream>>>(qkv, ctx);

  gemm_dbuf<0, float><<<dim3(DM / 128, SEQ / 64), 256, 0, stream>>>(
      ctx, Wout, out_b, nullptr, out, SEQ, DM, DM);
}